// Round 8
// baseline (92.150 us; speedup 1.0000x reference)
//
#include <hip/hip_runtime.h>
#include <math.h>

// Problem constants (B=16, T=2048, D=1024, K=8)
#define BT    32768   // B*T rows
#define DD    1024    // D
#define DV    256     // float4 per row (D/4)
#define KC    8       // clusters
#define NPART 1024    // kA grid (4 blocks/CU -> 16 waves/CU)
#define RPBA  32      // rows per kA block = BT/NPART
#define G3    2048    // kC grid (8 blocks/CU)
#define RPB3  16      // rows per kC block = BT/G3

// clang native vector type (required by __builtin_nontemporal_store).
typedef float fv4 __attribute__((ext_vector_type(4)));

// ---------------------------------------------------------------------------
// kA: partial column sums of x. Thread t owns fv4-column t; 8-deep batched
// loads. Grid 1024 (was 512 = 8 waves/CU, the round-5-measured 1.28 TB/s
// regime) -> 16 waves/CU, 131 KB in flight per CU.
// ---------------------------------------------------------------------------
__global__ __launch_bounds__(256) void kA_partial(const float* __restrict__ x,
                                                  float* __restrict__ part) {
    const int tid = threadIdx.x;
    const fv4* xv = (const fv4*)x;
    const long row0 = (long)blockIdx.x * RPBA;
    fv4 acc = (fv4)(0.f);

    for (int r = 0; r < RPBA; r += 8) {
        fv4 v[8];
#pragma unroll
        for (int i = 0; i < 8; ++i)
            v[i] = xv[(row0 + r + i) * DV + tid];
#pragma unroll
        for (int i = 0; i < 8; ++i) acc += v[i];
    }

    ((fv4*)part)[(long)blockIdx.x * DV + tid] = acc;
}

// ---------------------------------------------------------------------------
// kB: parallel fold. Block b reduces fv4-column b across NPART partial rows:
// thread t sums 4 strided rows, then LDS tree -> colsum[b]. All-L2, ~3 us.
// ---------------------------------------------------------------------------
__global__ __launch_bounds__(256) void kB_fold(const float* __restrict__ part,
                                               float* __restrict__ colsum) {
    const int tid = threadIdx.x;
    const int b = blockIdx.x;          // fv4-column index, 0..DV-1
    __shared__ fv4 red[256];

    fv4 a = (fv4)(0.f);
#pragma unroll
    for (int j = 0; j < NPART / 256; ++j)
        a += ((const fv4*)part)[(long)(tid + j * 256) * DV + b];
    red[tid] = a;
    __syncthreads();
#pragma unroll
    for (int s = 128; s > 0; s >>= 1) {
        if (tid < s) red[tid] += red[tid + s];
        __syncthreads();
    }
    if (tid == 0) ((fv4*)colsum)[b] = red[0];
}

// ---------------------------------------------------------------------------
// kC: responsibilities (redundant per block, ~2us aggregate) + famil/GELU.
// famil factorization: exp(-tau|x-mu_k|) = min(p*cp_k, q*cm_k) with
//   p = 2^(-tl*x), q = 2^(tl*x), cp_k = r_k*2^(tl*mu_k), cm_k = r_k*2^(-tl*mu_k)
// -> 2 exp2/element instead of 8 (trans pipe is quarter-rate; kC was
// trans-bound at ~30us vs its 21us memory floor). Wrong-branch product is
// bounded by r_k*e^(tau*(|x|+|mu|)) ~ 7e8, safely inside f32.
// ---------------------------------------------------------------------------
__global__ __launch_bounds__(256) void kC_main(const float* __restrict__ x,
                                               const float* __restrict__ mus,
                                               const float* __restrict__ wmix,
                                               const float* __restrict__ log_tau,
                                               const float* __restrict__ log_blend,
                                               const float* __restrict__ colsum,
                                               float* __restrict__ out) {
    const int tid = threadIdx.x;
    const long row0 = (long)blockIdx.x * RPB3;
    const fv4* xv = (const fv4*)x;

    // ---- responsibilities (redundant per block) --------------------------
    float rk[KC];
    {
        const float inv_bt = 1.0f / (float)BT;
        fv4 s = ((const fv4*)colsum)[tid];
        float m[4] = { s.x * inv_bt, s.y * inv_bt, s.z * inv_bt, s.w * inv_bt };
        float prt[KC];
#pragma unroll
        for (int k = 0; k < KC; ++k) {
            fv4 mu = ((const fv4*)mus)[k * DV + tid];
            float d0 = m[0] - mu.x, d1 = m[1] - mu.y;
            float d2 = m[2] - mu.z, d3 = m[3] - mu.w;
            prt[k] = d0 * d0 + d1 * d1 + d2 * d2 + d3 * d3;
        }
        __shared__ float l2[KC][4];
        const int lane = tid & 63, wv = tid >> 6;
#pragma unroll
        for (int k = 0; k < KC; ++k) {
            float v = prt[k];
#pragma unroll
            for (int off = 32; off > 0; off >>= 1) v += __shfl_down(v, off, 64);
            if (lane == 0) l2[k][wv] = v;
        }
        __syncthreads();
        float logits[KC], mx = -1e30f;
#pragma unroll
        for (int k = 0; k < KC; ++k) {
            float tot = l2[k][0] + l2[k][1] + l2[k][2] + l2[k][3];
            float dist = sqrtf(tot * (1.0f / (float)DD));
            logits[k] = logf(wmix[k]) - dist;
            mx = fmaxf(mx, logits[k]);
        }
        float se = 0.f, e[KC];
#pragma unroll
        for (int k = 0; k < KC; ++k) { e[k] = expf(logits[k] - mx); se += e[k]; }
        float is = 1.f / se;
#pragma unroll
        for (int k = 0; k < KC; ++k) rk[k] = e[k] * is;
    }

    // ---- per-column constants ---------------------------------------------
    const float LOG2E = 1.44269504f;
    fv4 lt = ((const fv4*)log_tau)[tid];
    fv4 lb = ((const fv4*)log_blend)[tid];
    float tl[4], al[4];
    tl[0] = __builtin_amdgcn_exp2f(lt.x * LOG2E) * LOG2E;
    tl[1] = __builtin_amdgcn_exp2f(lt.y * LOG2E) * LOG2E;
    tl[2] = __builtin_amdgcn_exp2f(lt.z * LOG2E) * LOG2E;
    tl[3] = __builtin_amdgcn_exp2f(lt.w * LOG2E) * LOG2E;
    al[0] = 1.f / (1.f + __builtin_amdgcn_exp2f(-lb.x * LOG2E));
    al[1] = 1.f / (1.f + __builtin_amdgcn_exp2f(-lb.y * LOG2E));
    al[2] = 1.f / (1.f + __builtin_amdgcn_exp2f(-lb.z * LOG2E));
    al[3] = 1.f / (1.f + __builtin_amdgcn_exp2f(-lb.w * LOG2E));

    float cp[KC][4], cm[KC][4];
#pragma unroll
    for (int k = 0; k < KC; ++k) {
        fv4 m4 = ((const fv4*)mus)[k * DV + tid];
        float me[4] = { m4.x, m4.y, m4.z, m4.w };
#pragma unroll
        for (int e = 0; e < 4; ++e) {
            float a = tl[e] * me[e];
            cp[k][e] = rk[k] * __builtin_amdgcn_exp2f(a);
            cm[k][e] = rk[k] * __builtin_amdgcn_exp2f(-a);
        }
    }

    // ---- famil / GELU main pass -------------------------------------------
    fv4* ov = (fv4*)out;
    for (int rr = 0; rr < RPB3; rr += 4) {
        fv4 v[4];
#pragma unroll
        for (int i = 0; i < 4; ++i)
            v[i] = xv[(row0 + rr + i) * DV + tid];
#pragma unroll
        for (int i = 0; i < 4; ++i) {
            float xin[4] = { v[i].x, v[i].y, v[i].z, v[i].w };
            float o[4];
#pragma unroll
            for (int e = 0; e < 4; ++e) {
                float xe = xin[e];
                float s = tl[e] * xe;
                float p = __builtin_amdgcn_exp2f(-s);
                float q = __builtin_amdgcn_exp2f(s);
                float fam = 0.f;
#pragma unroll
                for (int k = 0; k < KC; ++k)
                    fam += fminf(p * cp[k][e], q * cm[k][e]);
                float y = xe * (1.f - al[e] * fam);
                float z = 0.79788456f * (y + 0.044715f * y * y * y);
                float e2 = __builtin_amdgcn_exp2f(2.88539008f * z);
                float th = 1.f - 2.f * __builtin_amdgcn_rcpf(e2 + 1.f);
                o[e] = 0.5f * y * (1.f + th);
            }
            fv4 res; res.x = o[0]; res.y = o[1]; res.z = o[2]; res.w = o[3];
            __builtin_nontemporal_store(res, &ov[(row0 + rr + i) * DV + tid]);
        }
    }
}

extern "C" void kernel_launch(void* const* d_in, const int* in_sizes, int n_in,
                              void* d_out, int out_size, void* d_ws, size_t ws_size,
                              hipStream_t stream) {
    const float* x         = (const float*)d_in[0];
    const float* mus       = (const float*)d_in[1];
    const float* wmix      = (const float*)d_in[2];
    const float* log_tau   = (const float*)d_in[3];
    const float* log_blend = (const float*)d_in[4];
    float* out = (float*)d_out;

    float* part   = (float*)d_ws;             // NPART*DD floats (4 MB)
    float* colsum = part + (long)NPART * DD;  // DD floats (4 KB)

    kA_partial<<<NPART, 256, 0, stream>>>(x, part);
    kB_fold<<<DV, 256, 0, stream>>>(part, colsum);
    kC_main<<<G3, 256, 0, stream>>>(x, mus, wmix, log_tau, log_blend,
                                    colsum, out);
}

// Round 9
// 83.800 us; speedup vs baseline: 1.0996x; 1.0996x over previous
//
#include <hip/hip_runtime.h>
#include <math.h>

// Problem constants (B=16, T=2048, D=1024, K=8)
#define BT    32768   // B*T rows
#define DD    1024    // D
#define DV    256     // float4 per row (D/4)
#define KC    8       // clusters
#define NPART 512     // kA grid = number of partial-sum rows (round-7 proven)
#define G3    2048    // kC grid
#define RPB3  16      // rows per kC block = BT/G3

// clang native vector type (required by __builtin_nontemporal_store).
typedef float fv4 __attribute__((ext_vector_type(4)));

// ---------------------------------------------------------------------------
// kA: partial column sums of x (BT x DD). Thread t owns fv4-column t.
// 8-deep explicit load batching. Non-atomic stores. EXACTLY round-7's kA
// (part of the 83.3us run) — single-variable discipline this round.
// ---------------------------------------------------------------------------
__global__ __launch_bounds__(256) void kA_partial(const float* __restrict__ x,
                                                  float* __restrict__ part,
                                                  int rows_per_blk) {
    const int tid = threadIdx.x;
    const fv4* xv = (const fv4*)x;
    const long row0 = (long)blockIdx.x * rows_per_blk;
    fv4 acc = (fv4)(0.f);

    for (int r = 0; r < rows_per_blk; r += 8) {
        fv4 v[8];
#pragma unroll
        for (int i = 0; i < 8; ++i)
            v[i] = xv[(row0 + r + i) * DV + tid];
#pragma unroll
        for (int i = 0; i < 8; ++i) acc += v[i];
    }

    ((fv4*)part)[(long)blockIdx.x * DV + tid] = acc;
}

// ---------------------------------------------------------------------------
// kB: parallel fold. Block b reduces fv4-column b across the NPART partial
// rows (2 loads/thread + LDS tree) -> colsum[b]. EXACTLY round-7's kB.
// ---------------------------------------------------------------------------
__global__ __launch_bounds__(256) void kB_fold(const float* __restrict__ part,
                                               float* __restrict__ colsum) {
    const int tid = threadIdx.x;
    const int b = blockIdx.x;          // fv4-column index, 0..DV-1
    __shared__ fv4 red[256];

    fv4 a = ((const fv4*)part)[(long)tid * DV + b] +
            ((const fv4*)part)[(long)(tid + 256) * DV + b];
    red[tid] = a;
    __syncthreads();
#pragma unroll
    for (int s = 128; s > 0; s >>= 1) {
        if (tid < s) red[tid] += red[tid + s];
        __syncthreads();
    }
    if (tid == 0) ((fv4*)colsum)[b] = red[0];
}

// ---------------------------------------------------------------------------
// kC: responsibilities (redundant per block) + famil/GELU.
// Factorized famil (trans 10 -> 4 per element):
//   exp(-tau|x-mu_k|) = min(p*cp_k, q*cm_k),  p=2^(-tl*x), q=2^(tl*x),
//   cp_k = r_k*2^(tl*mu_k), cm_k = r_k*2^(-tl*mu_k)
// Round-8 lesson: cp/cm cost 64 VGPRs; pay for them by dropping the load
// batch from 4-deep to 2-deep (x read is L3-warm, 32 waves/CU hide it).
// Range safety: tl=2*log2e=2.885, |x|<5.5, |mu|<5 -> products < 2^31, f32-safe.
// ---------------------------------------------------------------------------
__global__ __launch_bounds__(256) void kC_main(const float* __restrict__ x,
                                               const float* __restrict__ mus,
                                               const float* __restrict__ wmix,
                                               const float* __restrict__ log_tau,
                                               const float* __restrict__ log_blend,
                                               const float* __restrict__ colsum,
                                               float* __restrict__ out) {
    const int tid = threadIdx.x;
    const long row0 = (long)blockIdx.x * RPB3;
    const fv4* xv = (const fv4*)x;

    // ---- responsibilities (redundant per block) --------------------------
    float rk[KC];
    {
        const float inv_bt = 1.0f / (float)BT;
        fv4 s = ((const fv4*)colsum)[tid];
        float m[4] = { s.x * inv_bt, s.y * inv_bt, s.z * inv_bt, s.w * inv_bt };
        float prt[KC];
#pragma unroll
        for (int k = 0; k < KC; ++k) {
            fv4 mu = ((const fv4*)mus)[k * DV + tid];
            float d0 = m[0] - mu.x, d1 = m[1] - mu.y;
            float d2 = m[2] - mu.z, d3 = m[3] - mu.w;
            prt[k] = d0 * d0 + d1 * d1 + d2 * d2 + d3 * d3;
        }
        __shared__ float l2[KC][4];
        const int lane = tid & 63, wv = tid >> 6;
#pragma unroll
        for (int k = 0; k < KC; ++k) {
            float v = prt[k];
#pragma unroll
            for (int off = 32; off > 0; off >>= 1) v += __shfl_down(v, off, 64);
            if (lane == 0) l2[k][wv] = v;
        }
        __syncthreads();
        float logits[KC], mx = -1e30f;
#pragma unroll
        for (int k = 0; k < KC; ++k) {
            float tot = l2[k][0] + l2[k][1] + l2[k][2] + l2[k][3];
            float dist = sqrtf(tot * (1.0f / (float)DD));
            logits[k] = logf(wmix[k]) - dist;
            mx = fmaxf(mx, logits[k]);
        }
        float se = 0.f, e[KC];
#pragma unroll
        for (int k = 0; k < KC; ++k) { e[k] = expf(logits[k] - mx); se += e[k]; }
        float is = 1.f / se;
#pragma unroll
        for (int k = 0; k < KC; ++k) rk[k] = e[k] * is;
    }

    // ---- per-column constants --------------------------------------------
    const float LOG2E = 1.44269504f;
    fv4 lt = ((const fv4*)log_tau)[tid];
    fv4 lb = ((const fv4*)log_blend)[tid];
    float tl[4], al[4];
    tl[0] = __builtin_amdgcn_exp2f(lt.x * LOG2E) * LOG2E;
    tl[1] = __builtin_amdgcn_exp2f(lt.y * LOG2E) * LOG2E;
    tl[2] = __builtin_amdgcn_exp2f(lt.z * LOG2E) * LOG2E;
    tl[3] = __builtin_amdgcn_exp2f(lt.w * LOG2E) * LOG2E;
    al[0] = 1.f / (1.f + __builtin_amdgcn_exp2f(-lb.x * LOG2E));
    al[1] = 1.f / (1.f + __builtin_amdgcn_exp2f(-lb.y * LOG2E));
    al[2] = 1.f / (1.f + __builtin_amdgcn_exp2f(-lb.z * LOG2E));
    al[3] = 1.f / (1.f + __builtin_amdgcn_exp2f(-lb.w * LOG2E));

    float cp[KC][4], cm[KC][4];
#pragma unroll
    for (int k = 0; k < KC; ++k) {
        fv4 m4 = ((const fv4*)mus)[k * DV + tid];
        float me[4] = { m4.x, m4.y, m4.z, m4.w };
#pragma unroll
        for (int e = 0; e < 4; ++e) {
            float a = tl[e] * me[e];
            cp[k][e] = rk[k] * __builtin_amdgcn_exp2f(a);
            cm[k][e] = rk[k] * __builtin_amdgcn_exp2f(-a);
        }
    }

    // ---- famil / GELU main pass (2-deep batch: register-lean) ------------
    fv4* ov = (fv4*)out;
    for (int rr = 0; rr < RPB3; rr += 2) {
        fv4 v[2];
#pragma unroll
        for (int i = 0; i < 2; ++i)
            v[i] = xv[(row0 + rr + i) * DV + tid];
#pragma unroll
        for (int i = 0; i < 2; ++i) {
            float xin[4] = { v[i].x, v[i].y, v[i].z, v[i].w };
            float o[4];
#pragma unroll
            for (int e = 0; e < 4; ++e) {
                float xe = xin[e];
                float s = tl[e] * xe;
                float p = __builtin_amdgcn_exp2f(-s);
                float q = __builtin_amdgcn_exp2f(s);
                float fam = 0.f;
#pragma unroll
                for (int k = 0; k < KC; ++k)
                    fam += fminf(p * cp[k][e], q * cm[k][e]);
                float y = xe * (1.f - al[e] * fam);
                float z = 0.79788456f * (y + 0.044715f * y * y * y);
                float e2 = __builtin_amdgcn_exp2f(2.88539008f * z);
                o[e] = y * (1.f - __builtin_amdgcn_rcpf(e2 + 1.f));
            }
            fv4 res; res.x = o[0]; res.y = o[1]; res.z = o[2]; res.w = o[3];
            __builtin_nontemporal_store(res, &ov[(row0 + rr + i) * DV + tid]);
        }
    }
}

extern "C" void kernel_launch(void* const* d_in, const int* in_sizes, int n_in,
                              void* d_out, int out_size, void* d_ws, size_t ws_size,
                              hipStream_t stream) {
    const float* x         = (const float*)d_in[0];
    const float* mus       = (const float*)d_in[1];
    const float* wmix      = (const float*)d_in[2];
    const float* log_tau   = (const float*)d_in[3];
    const float* log_blend = (const float*)d_in[4];
    float* out = (float*)d_out;

    float* part   = (float*)d_ws;             // NPART*DD floats (2 MB)
    float* colsum = part + (long)NPART * DD;  // DD floats (4 KB)

    kA_partial<<<NPART, 256, 0, stream>>>(x, part, BT / NPART);
    kB_fold<<<DV, 256, 0, stream>>>(part, colsum);
    kC_main<<<G3, 256, 0, stream>>>(x, mus, wmix, log_tau, log_blend,
                                    colsum, out);
}